// Round 2
// baseline (400.965 us; speedup 1.0000x reference)
//
#include <hip/hip_runtime.h>
#include <cstdint>
#include <cstddef>

typedef _Float16 f16;
typedef f16 f16x2 __attribute__((ext_vector_type(2)));
typedef f16 f16x4 __attribute__((ext_vector_type(4)));
typedef f16 f16x8 __attribute__((ext_vector_type(8)));
typedef float f32x4 __attribute__((ext_vector_type(4)));

#define NEXP 8
#define BM 128
#define BN 128
#define BK 32

// async global->LDS, 16B per lane. LDS dest must be wave-uniform base + lane*16
// (staging index is tid*16 so this holds). Global source may be per-lane
// arbitrary (gathered rows / swizzled chunks are fine).
__device__ __forceinline__ void async_cp16(void* lds, const void* gsrc) {
  __builtin_amdgcn_global_load_lds(
      (const __attribute__((address_space(1))) void*)gsrc,
      (__attribute__((address_space(3))) void*)lds, 16, 0, 0);
}

// ---------------- K0: transpose gate weights gw[D,8] -> gwT[8,D] ----------------
__global__ __launch_bounds__(256) void k_gwT(const float* __restrict__ gw,
                                             float* __restrict__ gwT, int D) {
  int i = blockIdx.x * 256 + threadIdx.x;   // i < 8*D
  int e = i / D, d = i - e * D;
  gwT[i] = gw[d * NEXP + e];
}

// ---------------- K1: fused x->f16 convert + fp32 gating ----------------
// 256 threads = 4 waves; block owns 16 tokens (4 per wave).
// Wave lane layout for the dot: lane = dhalf*32 + tl*8 + e.
__global__ __launch_bounds__(256) void k_gate2(
    const float* __restrict__ x, const float* __restrict__ gwT,
    f16* __restrict__ xb, int* __restrict__ gate, float* __restrict__ scale,
    int* __restrict__ cnt, float* __restrict__ probsum, int D)
{
  __shared__ float lps[NEXP];
  __shared__ int lcnt[NEXP];
  int tid = threadIdx.x;
  if (tid < NEXP) { lps[tid] = 0.f; lcnt[tid] = 0; }
  __syncthreads();

  int t0 = blockIdx.x * 16;

  // phase 1: convert this block's 16 rows fp32 -> f16 (fully coalesced; also
  // warms L1/L2 with exactly the x data the dot below re-reads)
  for (int row = 0; row < 16; row++) {
    const float* xr = x + (size_t)(t0 + row) * D;
    f16* xo = xb + (size_t)(t0 + row) * D;
    for (int cdx = tid * 4; cdx < D; cdx += 1024) {
      float4 v = *(const float4*)(xr + cdx);
      f16x4 h; h[0] = (f16)v.x; h[1] = (f16)v.y; h[2] = (f16)v.z; h[3] = (f16)v.w;
      *(f16x4*)(xo + cdx) = h;
    }
  }

  // phase 2: fp32 gating dot (exact-enough argmax: fp32 inputs, fp32 accum)
  int lane = tid & 63, w = tid >> 6;
  int dh = lane >> 5;            // D-half
  int tl = (lane >> 3) & 3;      // token within wave
  int e  = lane & 7;             // expert
  int tok = t0 + w * 4 + tl;
  int halfD = D >> 1;
  const float* xr = x + (size_t)tok * D + dh * halfD;
  const float* gr = gwT + (size_t)e * D + dh * halfD;
  float acc = 0.f;
  for (int d = 0; d < halfD; d += 4) {
    float4 xv = *(const float4*)(xr + d);
    float4 gv = *(const float4*)(gr + d);
    acc += xv.x * gv.x + xv.y * gv.y + xv.z * gv.z + xv.w * gv.w;
  }
  acc += __shfl_xor(acc, 32);    // combine D-halves; lanes 0..31 now full logits

  float v = acc;
  float m = v;
  m = fmaxf(m, __shfl_xor(m, 1));
  m = fmaxf(m, __shfl_xor(m, 2));
  m = fmaxf(m, __shfl_xor(m, 4));
  float pe = __expf(v - m);
  float s = pe;
  s += __shfl_xor(s, 1); s += __shfl_xor(s, 2); s += __shfl_xor(s, 4);
  int candv = (v == m) ? e : NEXP;               // first-max tie-break (min e)
  int g = candv;
  g = min(g, __shfl_xor(g, 1)); g = min(g, __shfl_xor(g, 2)); g = min(g, __shfl_xor(g, 4));
  float pg = __shfl(pe, (lane & 56) + g);        // pe at the argmax lane of my 8-group

  if (lane < 32) {
    atomicAdd(&lps[e], pe / s);
    if (e == 0) {
      gate[tok] = g;
      scale[tok] = pg / s;
      atomicAdd(&lcnt[g], 1);
    }
  }
  __syncthreads();
  if (tid < NEXP) {
    atomicAdd(&probsum[tid], lps[tid]);
    atomicAdd(&cnt[tid], lcnt[tid]);
  }
}

// ---------------- K2: build Wfull^T in fp16 ----------------
// wt[e][n][d] = sum_p rule[e,p,a,b] * W[e,p,i,j], d = a*Dp+i, n = b*Op+j.
// n-major, d contiguous (K-contiguous for GEMM B staging).
__global__ __launch_bounds__(256) void k_wfull(
    const float* __restrict__ Wp, const float* __restrict__ rule,
    f16* __restrict__ wt, int Dp, int Op, int D, int O)
{
  int bid = blockIdx.x;
  int it = Dp >> 5, jt = Op >> 5;
  int itile = bid % it; bid /= it;
  int jtile = bid % jt; bid /= jt;
  int b = bid & 3; bid >>= 2;
  int e = bid;
  int i0 = itile * 32, j0 = jtile * 32;

  __shared__ float Wt[4][32][33];
  int tid = threadIdx.x;
  for (int idx = tid; idx < 4096; idx += 256) {
    int p = idx >> 10, rem = idx & 1023, ii = rem >> 5, jj = rem & 31;
    Wt[p][ii][jj] = Wp[(size_t)((e * 4 + p) * Dp + i0 + ii) * Op + j0 + jj];
  }
  float s[4][4];
#pragma unroll
  for (int p = 0; p < 4; p++)
#pragma unroll
    for (int a = 0; a < 4; a++)
      s[p][a] = rule[((e * 4 + p) * 4 + a) * 4 + b];
  __syncthreads();

  int ii = (tid & 15) * 2, jjb = tid >> 4;
#pragma unroll
  for (int a = 0; a < 4; a++) {
#pragma unroll
    for (int jp = 0; jp < 2; jp++) {
      int jj = jjb + jp * 16;
      float v0 = 0.f, v1 = 0.f;
#pragma unroll
      for (int p = 0; p < 4; p++) {
        v0 += s[p][a] * Wt[p][ii][jj];
        v1 += s[p][a] * Wt[p][ii + 1][jj];
      }
      size_t n = (size_t)b * Op + j0 + jj;
      size_t dd = (size_t)a * Dp + i0 + ii;
      f16x2 hv; hv[0] = (f16)v0; hv[1] = (f16)v1;
      *(f16x2*)(wt + ((size_t)e * O + n) * D + dd) = hv;
    }
  }
}

// ---------------- K3: plan (scan, loss, descriptors) ----------------
__global__ void k_plan(const int* __restrict__ cnt, const float* __restrict__ probsum,
                       int* __restrict__ offs, int* __restrict__ ndesc,
                       int2* __restrict__ desc, float* __restrict__ otail, int T)
{
  if (threadIdx.x != 0 || blockIdx.x != 0) return;
  int off = 0, nd = 0; float loss = 0.f;
  for (int e = 0; e < NEXP; e++) {
    offs[e] = off;
    int c = cnt[e];
    loss += probsum[e] * (float)c;
    for (int m0 = 0; m0 < c; m0 += BM) { desc[nd] = make_int2(e, m0); nd++; }
    off += c;
  }
  offs[NEXP] = off;
  *ndesc = nd;
  float invT = 1.0f / (float)T;
  otail[0] = (float)NEXP * loss * invT * invT;  // balance loss
  for (int e = 0; e < NEXP; e++) otail[1 + e] = (float)cnt[e];  // num_tokens
}

// ---------------- K4: scatter tokens by expert ----------------
__global__ __launch_bounds__(256) void k_scatter(
    const int* __restrict__ gate, const int* __restrict__ offs,
    int* __restrict__ cursor, int* __restrict__ perm)
{
  int t = blockIdx.x * 256 + threadIdx.x;
  int g = gate[t];
  int lane = threadIdx.x & 63;
  int pos = 0;
#pragma unroll
  for (int e = 0; e < NEXP; e++) {
    unsigned long long mask = __ballot(g == e);
    if (mask == 0ull) continue;            // wave-uniform
    int leader = __ffsll((unsigned long long)mask) - 1;
    int base = 0;
    if (lane == leader) base = atomicAdd(&cursor[e], (int)__popcll(mask));
    base = __shfl(base, leader);
    if (g == e) {
      int below = (int)__popcll(mask & ((1ull << lane) - 1ull));
      pos = offs[e] + base + below;
    }
  }
  perm[pos] = t;
}

// ---------------- K5: gathered top-1 GEMM ----------------
// 128x128 tile, BK=32, double-buffered LDS, fine-grained vmcnt barriers
// (prefetch of tile k+1 stays in flight across the barrier), XOR bank swizzle.
__global__ __launch_bounds__(256) void k_gemm(
    const f16* __restrict__ xb, const f16* __restrict__ wt,
    const float* __restrict__ bias, const int* __restrict__ perm,
    const int* __restrict__ cnt, const int* __restrict__ offs,
    const int* __restrict__ ndesc, const int2* __restrict__ desc,
    const float* __restrict__ scale, float* __restrict__ out, int D, int O)
{
  if ((int)blockIdx.x >= *ndesc) return;
  int2 dsc = desc[blockIdx.x];
  int e = dsc.x, m0 = dsc.y;
  int ce = cnt[e];
  int seg = offs[e];
  int n0 = blockIdx.y * BN;

  __shared__ f16 Al[2][BM * BK];
  __shared__ f16 Bl[2][BN * BK];
  __shared__ int tokS[BM];
  __shared__ float scS[BM];

  int tid = threadIdx.x;
  if (tid < BM) {
    int idx = m0 + tid; if (idx > ce - 1) idx = ce - 1;  // clamp partial tile
    int tok = perm[seg + idx];
    tokS[tid] = tok;
    scS[tid] = scale[tok];
  }
  __syncthreads();

  // staging: thread owns LDS slot (row r, chunk c); fetches global chunk
  // gc = c ^ ((r>>1)&3). Reader un-swizzles with the same xor.
  int r = tid >> 2;   // dest row 0..63 (and r+64)
  int c = tid & 3;
  int gc = c ^ ((r >> 1) & 3);   // ((r+64)>>1)&3 == (r>>1)&3, so gc valid for both rows
  const f16* a1 = xb + (size_t)tokS[r] * D + gc * 8;
  const f16* a2 = xb + (size_t)tokS[r + 64] * D + gc * 8;
  const f16* b1 = wt + ((size_t)e * O + n0 + r) * D + gc * 8;
  const f16* b2 = wt + ((size_t)e * O + n0 + r + 64) * D + gc * 8;

  int lane = tid & 63;
  int w = tid >> 6;
  int wm = (w & 1) * 64, wn = (w >> 1) * 64;
  int lr = lane & 15, q = lane >> 4;
  int qs = q ^ ((lr >> 1) & 3);  // swizzled read chunk (wm/wn/mi*16 are 0 mod 8 after >>1&3)

  f32x4 acc[4][4] = {};
  int nk = D / BK;

#define STAGE(kk, p)                                             \
  do {                                                           \
    async_cp16(&Al[(p)][tid * 8], a1 + (kk) * BK);               \
    async_cp16(&Al[(p)][2048 + tid * 8], a2 + (kk) * BK);        \
    async_cp16(&Bl[(p)][tid * 8], b1 + (kk) * BK);               \
    async_cp16(&Bl[(p)][2048 + tid * 8], b2 + (kk) * BK);        \
  } while (0)

  STAGE(0, 0);
  STAGE(1, 1);

  for (int kk = 0; kk < nk; ++kk) {
    int p = kk & 1;
    // wait: tile kk complete; tile kk+1's 4 loads may stay in flight
    if (kk + 1 < nk)
      asm volatile("s_waitcnt vmcnt(4)\n\ts_barrier" ::: "memory");
    else
      asm volatile("s_waitcnt vmcnt(0)\n\ts_barrier" ::: "memory");

    f16x8 af[4], bf[4];
#pragma unroll
    for (int mi = 0; mi < 4; mi++)
      af[mi] = *(const f16x8*)&Al[p][(wm + mi * 16 + lr) * BK + qs * 8];
#pragma unroll
    for (int ni = 0; ni < 4; ni++)
      bf[ni] = *(const f16x8*)&Bl[p][(wn + ni * 16 + lr) * BK + qs * 8];

    // all waves' ds_reads of buffer p done -> safe to restage it
    asm volatile("s_waitcnt lgkmcnt(0)\n\ts_barrier" ::: "memory");
    if (kk + 2 < nk) STAGE(kk + 2, p);

#pragma unroll
    for (int mi = 0; mi < 4; mi++)
#pragma unroll
      for (int ni = 0; ni < 4; ni++)
        acc[mi][ni] = __builtin_amdgcn_mfma_f32_16x16x32_f16(
            af[mi], bf[ni], acc[mi][ni], 0, 0, 0);
  }
#undef STAGE

  // epilogue: C/D layout col=lane&15, row=(lane>>4)*4+reg
  float bv[4];
#pragma unroll
  for (int ni = 0; ni < 4; ni++)
    bv[ni] = bias[(size_t)e * O + n0 + wn + ni * 16 + lr];
#pragma unroll
  for (int mi = 0; mi < 4; mi++) {
#pragma unroll
    for (int rg = 0; rg < 4; rg++) {
      int rl = wm + mi * 16 + q * 4 + rg;
      if (m0 + rl < ce) {
        float s = scS[rl];
        float* orow = out + (size_t)tokS[rl] * O + n0 + wn;
#pragma unroll
        for (int ni = 0; ni < 4; ni++)
          orow[ni * 16 + lr] = (acc[mi][ni][rg] + bv[ni]) * s;
      }
    }
  }
}

extern "C" void kernel_launch(void* const* d_in, const int* in_sizes, int n_in,
                              void* d_out, int out_size, void* d_ws, size_t ws_size,
                              hipStream_t stream)
{
  const float* x    = (const float*)d_in[0];   // [T, D]
  const float* gw   = (const float*)d_in[1];   // [D, 8]
  const float* rule = (const float*)d_in[2];   // [8, 4, 4, 4]
  const float* W    = (const float*)d_in[3];   // [8, 4, D/4, O/4]
  const float* bias = (const float*)d_in[4];   // [8, O]
  float* out = (float*)d_out;

  int D = in_sizes[1] / NEXP;
  int O = in_sizes[4] / NEXP;
  int T = in_sizes[0] / D;
  int Dp = D / 4, Op = O / 4;

  uint8_t* ws = (uint8_t*)d_ws;
  size_t off = 0;
  f16* xb = (f16*)(ws + off);  off += (size_t)T * D * 2;
  f16* wt = (f16*)(ws + off);  off += (size_t)NEXP * O * D * 2;
  int*   gate  = (int*)(ws + off);   off += (size_t)T * 4;
  float* scale = (float*)(ws + off); off += (size_t)T * 4;
  int*   perm  = (int*)(ws + off);   off += (size_t)T * 4;
  off = (off + 255) & ~(size_t)255;
  uint8_t* C = ws + off;
  int*   cnt     = (int*)(C + 0);
  float* probsum = (float*)(C + 32);
  int*   cursor  = (int*)(C + 64);
  int*   ndesc   = (int*)(C + 96);
  int*   offs    = (int*)(C + 128);
  int2*  desc    = (int2*)(C + 192);   // capacity to C+4096
  float* gwT     = (float*)(C + 4096); // [8, D] fp32

  // zero cnt/probsum/cursor/ndesc (ws is re-poisoned 0xAA before every call)
  hipMemsetAsync(C, 0, 128, stream);

  k_gwT<<<(NEXP * D) / 256, 256, 0, stream>>>(gw, gwT, D);
  k_gate2<<<T / 16, 256, 0, stream>>>(x, gwT, xb, gate, scale, cnt, probsum, D);
  k_wfull<<<NEXP * 4 * (Op / 32) * (Dp / 32), 256, 0, stream>>>(W, rule, wt, Dp, Op, D, O);
  k_plan<<<1, 1, 0, stream>>>(cnt, probsum, offs, ndesc, desc, out + (size_t)T * O, T);
  k_scatter<<<T / 256, 256, 0, stream>>>(gate, offs, cursor, perm);

  int maxdesc = T / BM + NEXP;  // worst-case row-block descriptor count
  k_gemm<<<dim3(maxdesc, O / BN), 256, 0, stream>>>(
      xb, wt, bias, perm, cnt, offs, ndesc, desc, scale, out, D, O);
}

// Round 3
// 389.092 us; speedup vs baseline: 1.0305x; 1.0305x over previous
//
#include <hip/hip_runtime.h>
#include <cstdint>
#include <cstddef>

typedef _Float16 f16;
typedef f16 f16x2 __attribute__((ext_vector_type(2)));
typedef f16 f16x4 __attribute__((ext_vector_type(4)));
typedef f16 f16x8 __attribute__((ext_vector_type(8)));
typedef float f32x4 __attribute__((ext_vector_type(4)));

#define NEXP 8
#define BM 128
#define BN 256
#define BK 32

// async global->LDS, 16B per lane. LDS dest must be wave-uniform base + lane*16
// (staging index is tid*16 so this holds). Global source may be per-lane
// arbitrary (gathered rows / swizzled chunks are fine).
__device__ __forceinline__ void async_cp16(void* lds, const void* gsrc) {
  __builtin_amdgcn_global_load_lds(
      (const __attribute__((address_space(1))) void*)gsrc,
      (__attribute__((address_space(3))) void*)lds, 16, 0, 0);
}

// ---------------- K1: gating + x -> fp16 (round-1 version: single x pass) ----
// 256 threads = 4 waves, one token per wave. gw (64KB) is L2-resident.
__global__ __launch_bounds__(256) void k_gate(
    const float* __restrict__ x, const float* __restrict__ gw,
    f16* __restrict__ xb, int* __restrict__ gate, float* __restrict__ scale,
    int* __restrict__ cnt, float* __restrict__ probsum, int D)
{
  __shared__ float ps[NEXP];
  __shared__ int pc[NEXP];
  int tid = threadIdx.x, lane = tid & 63, w = tid >> 6;
  if (tid < NEXP) { ps[tid] = 0.f; pc[tid] = 0; }
  __syncthreads();

  int t = blockIdx.x * 4 + w;
  const float* xr = x + (size_t)t * D;
  f16* xbr = xb + (size_t)t * D;

  float acc[NEXP] = {};
  for (int d0 = lane * 4; d0 < D; d0 += 256) {
    float4 v = *(const float4*)(xr + d0);
    f16x4 h; h[0] = (f16)v.x; h[1] = (f16)v.y; h[2] = (f16)v.z; h[3] = (f16)v.w;
    *(f16x4*)(xbr + d0) = h;
    const float* g0 = gw + (size_t)d0 * NEXP;
    float xv[4] = {v.x, v.y, v.z, v.w};
#pragma unroll
    for (int j = 0; j < 4; j++) {
      float4 ga = *(const float4*)(g0 + j * NEXP);
      float4 gb = *(const float4*)(g0 + j * NEXP + 4);
      acc[0] += xv[j] * ga.x; acc[1] += xv[j] * ga.y;
      acc[2] += xv[j] * ga.z; acc[3] += xv[j] * ga.w;
      acc[4] += xv[j] * gb.x; acc[5] += xv[j] * gb.y;
      acc[6] += xv[j] * gb.z; acc[7] += xv[j] * gb.w;
    }
  }
#pragma unroll
  for (int e = 0; e < NEXP; e++) {
    float v = acc[e];
    for (int o = 32; o > 0; o >>= 1) v += __shfl_xor(v, o);
    acc[e] = v;
  }
  if (lane == 0) {
    float m = acc[0]; int g = 0;
#pragma unroll
    for (int e = 1; e < NEXP; e++) if (acc[e] > m) { m = acc[e]; g = e; }
    float pr[NEXP]; float ssum = 0.f;
#pragma unroll
    for (int e = 0; e < NEXP; e++) { pr[e] = __expf(acc[e] - m); ssum += pr[e]; }
    float inv = 1.0f / ssum;
#pragma unroll
    for (int e = 0; e < NEXP; e++) atomicAdd(&ps[e], pr[e] * inv);
    atomicAdd(&pc[g], 1);
    gate[t] = g;
    scale[t] = pr[g] * inv;
  }
  __syncthreads();
  if (tid < NEXP) {
    atomicAdd(&probsum[tid], ps[tid]);
    atomicAdd(&cnt[tid], pc[tid]);
  }
}

// ---------------- K2: build Wfull^T in fp16 ----------------
// wt[e][n][d] = sum_p rule[e,p,a,b] * W[e,p,i,j], d = a*Dp+i, n = b*Op+j.
// n-major, d contiguous. b looped in-block: W tile read once, used for all 4 b.
__global__ __launch_bounds__(256) void k_wfull(
    const float* __restrict__ Wp, const float* __restrict__ rule,
    f16* __restrict__ wt, int Dp, int Op, int D, int O)
{
  int bid = blockIdx.x;
  int it = Dp >> 5, jt = Op >> 5;
  int itile = bid % it; bid /= it;
  int jtile = bid % jt; bid /= jt;
  int e = bid;
  int i0 = itile * 32, j0 = jtile * 32;

  __shared__ float Wt[4][32][33];
  int tid = threadIdx.x;
  for (int idx = tid; idx < 4096; idx += 256) {
    int p = idx >> 10, rem = idx & 1023, ii = rem >> 5, jj = rem & 31;
    Wt[p][ii][jj] = Wp[(size_t)((e * 4 + p) * Dp + i0 + ii) * Op + j0 + jj];
  }
  __syncthreads();

  int ii = (tid & 15) * 2, jjb = tid >> 4;
#pragma unroll
  for (int b = 0; b < 4; b++) {
    float s[4][4];
#pragma unroll
    for (int p = 0; p < 4; p++)
#pragma unroll
      for (int a = 0; a < 4; a++)
        s[p][a] = rule[((e * 4 + p) * 4 + a) * 4 + b];
#pragma unroll
    for (int a = 0; a < 4; a++) {
#pragma unroll
      for (int jp = 0; jp < 2; jp++) {
        int jj = jjb + jp * 16;
        float v0 = 0.f, v1 = 0.f;
#pragma unroll
        for (int p = 0; p < 4; p++) {
          v0 += s[p][a] * Wt[p][ii][jj];
          v1 += s[p][a] * Wt[p][ii + 1][jj];
        }
        size_t n = (size_t)b * Op + j0 + jj;
        size_t dd = (size_t)a * Dp + i0 + ii;
        f16x2 hv; hv[0] = (f16)v0; hv[1] = (f16)v1;
        *(f16x2*)(wt + ((size_t)e * O + n) * D + dd) = hv;
      }
    }
  }
}

// ---------------- K3: plan (scan, loss, descriptors) ----------------
__global__ void k_plan(const int* __restrict__ cnt, const float* __restrict__ probsum,
                       int* __restrict__ offs, int* __restrict__ ndesc,
                       int2* __restrict__ desc, float* __restrict__ otail, int T)
{
  if (threadIdx.x != 0 || blockIdx.x != 0) return;
  int off = 0, nd = 0; float loss = 0.f;
  for (int e = 0; e < NEXP; e++) {
    offs[e] = off;
    int c = cnt[e];
    loss += probsum[e] * (float)c;
    for (int m0 = 0; m0 < c; m0 += BM) { desc[nd] = make_int2(e, m0); nd++; }
    off += c;
  }
  offs[NEXP] = off;
  *ndesc = nd;
  float invT = 1.0f / (float)T;
  otail[0] = (float)NEXP * loss * invT * invT;  // balance loss
  for (int e = 0; e < NEXP; e++) otail[1 + e] = (float)cnt[e];  // num_tokens
}

// ---------------- K4: scatter tokens by expert ----------------
__global__ __launch_bounds__(256) void k_scatter(
    const int* __restrict__ gate, const int* __restrict__ offs,
    int* __restrict__ cursor, int* __restrict__ perm)
{
  int t = blockIdx.x * 256 + threadIdx.x;
  int g = gate[t];
  int lane = threadIdx.x & 63;
  int pos = 0;
#pragma unroll
  for (int e = 0; e < NEXP; e++) {
    unsigned long long mask = __ballot(g == e);
    if (mask == 0ull) continue;            // wave-uniform
    int leader = __ffsll((unsigned long long)mask) - 1;
    int base = 0;
    if (lane == leader) base = atomicAdd(&cursor[e], (int)__popcll(mask));
    base = __shfl(base, leader);
    if (g == e) {
      int below = (int)__popcll(mask & ((1ull << lane) - 1ull));
      pos = offs[e] + base + below;
    }
  }
  perm[pos] = t;
}

// ---------------- K5: gathered top-1 GEMM ----------------
// Block tile 128x256, BK=32, 4 waves each 64x128 (4x8 frags of 16x16x32 f16):
// 12 ds_read_b128 per 32 MFMA per wave (vs 8 per 16 before, -25% LDS/MFMA).
// Double-buffered LDS, fine-grained vmcnt barriers, XOR bank swizzle.
// Grid (ncol fastest): consecutive blocks share the gathered A tile (L2 reuse).
__global__ __launch_bounds__(256) void k_gemm(
    const f16* __restrict__ xb, const f16* __restrict__ wt,
    const float* __restrict__ bias, const int* __restrict__ perm,
    const int* __restrict__ cnt, const int* __restrict__ offs,
    const int* __restrict__ ndesc, const int2* __restrict__ desc,
    const float* __restrict__ scale, float* __restrict__ out, int D, int O)
{
  if ((int)blockIdx.y >= *ndesc) return;
  int2 dsc = desc[blockIdx.y];
  int e = dsc.x, m0 = dsc.y;
  int ce = cnt[e];
  int seg = offs[e];
  int n0 = blockIdx.x * BN;

  __shared__ f16 Al[2][BM * BK];   // 2 x 8KB
  __shared__ f16 Bl[2][BN * BK];   // 2 x 16KB
  __shared__ int tokS[BM];
  __shared__ float scS[BM];

  int tid = threadIdx.x;
  if (tid < BM) {
    int idx = m0 + tid; if (idx > ce - 1) idx = ce - 1;  // clamp partial tile
    int tok = perm[seg + idx];
    tokS[tid] = tok;
    scS[tid] = scale[tok];
  }
  __syncthreads();

  // staging: thread owns 16B chunk c of row r (and r+64 / r+128 / r+192 for B);
  // fetches global chunk gc = c ^ ((r>>1)&3); reader un-swizzles with same xor.
  int r = tid >> 2;   // 0..63
  int c = tid & 3;
  int gc = c ^ ((r >> 1) & 3);   // (r+64k)>>1 keeps &3, so gc valid for all row groups
  const f16* a1 = xb + (size_t)tokS[r] * D + gc * 8;
  const f16* a2 = xb + (size_t)tokS[r + 64] * D + gc * 8;
  const f16* bp0 = wt + ((size_t)e * O + n0 + r) * D + gc * 8;
  const f16* bp1 = wt + ((size_t)e * O + n0 + r + 64) * D + gc * 8;
  const f16* bp2 = wt + ((size_t)e * O + n0 + r + 128) * D + gc * 8;
  const f16* bp3 = wt + ((size_t)e * O + n0 + r + 192) * D + gc * 8;

  int lane = tid & 63;
  int w = tid >> 6;
  int wm = (w & 1) * 64, wn = (w >> 1) * 128;
  int lr = lane & 15, q = lane >> 4;
  int qs = q ^ ((lr >> 1) & 3);  // swizzled read chunk

  f32x4 acc[4][8] = {};
  int nk = D / BK;

#define STAGE(kk, p)                                              \
  do {                                                            \
    async_cp16(&Al[(p)][tid * 8], a1 + (kk) * BK);                \
    async_cp16(&Al[(p)][2048 + tid * 8], a2 + (kk) * BK);         \
    async_cp16(&Bl[(p)][tid * 8], bp0 + (kk) * BK);               \
    async_cp16(&Bl[(p)][2048 + tid * 8], bp1 + (kk) * BK);        \
    async_cp16(&Bl[(p)][4096 + tid * 8], bp2 + (kk) * BK);        \
    async_cp16(&Bl[(p)][6144 + tid * 8], bp3 + (kk) * BK);        \
  } while (0)

  STAGE(0, 0);
  STAGE(1, 1);

  for (int kk = 0; kk < nk; ++kk) {
    int p = kk & 1;
    // wait: tile kk's 6 loads done; tile kk+1's 6 may stay in flight
    if (kk + 1 < nk)
      asm volatile("s_waitcnt vmcnt(6)\n\ts_barrier" ::: "memory");
    else
      asm volatile("s_waitcnt vmcnt(0)\n\ts_barrier" ::: "memory");

    f16x8 af[4], bf[8];
#pragma unroll
    for (int mi = 0; mi < 4; mi++)
      af[mi] = *(const f16x8*)&Al[p][(wm + mi * 16 + lr) * BK + qs * 8];
#pragma unroll
    for (int ni = 0; ni < 8; ni++)
      bf[ni] = *(const f16x8*)&Bl[p][(wn + ni * 16 + lr) * BK + qs * 8];

    // all waves' ds_reads of buffer p done -> safe to restage it
    asm volatile("s_waitcnt lgkmcnt(0)\n\ts_barrier" ::: "memory");
    if (kk + 2 < nk) STAGE(kk + 2, p);

#pragma unroll
    for (int mi = 0; mi < 4; mi++)
#pragma unroll
      for (int ni = 0; ni < 8; ni++)
        acc[mi][ni] = __builtin_amdgcn_mfma_f32_16x16x32_f16(
            af[mi], bf[ni], acc[mi][ni], 0, 0, 0);
  }
#undef STAGE

  // epilogue: C/D layout col=lane&15, row=(lane>>4)*4+reg
  float bv[8];
#pragma unroll
  for (int ni = 0; ni < 8; ni++)
    bv[ni] = bias[(size_t)e * O + n0 + wn + ni * 16 + lr];
#pragma unroll
  for (int mi = 0; mi < 4; mi++) {
#pragma unroll
    for (int rg = 0; rg < 4; rg++) {
      int rl = wm + mi * 16 + q * 4 + rg;
      if (m0 + rl < ce) {
        float s = scS[rl];
        float* orow = out + (size_t)tokS[rl] * O + n0 + wn;
#pragma unroll
        for (int ni = 0; ni < 8; ni++)
          orow[ni * 16 + lr] = (acc[mi][ni][rg] + bv[ni]) * s;
      }
    }
  }
}

extern "C" void kernel_launch(void* const* d_in, const int* in_sizes, int n_in,
                              void* d_out, int out_size, void* d_ws, size_t ws_size,
                              hipStream_t stream)
{
  const float* x    = (const float*)d_in[0];   // [T, D]
  const float* gw   = (const float*)d_in[1];   // [D, 8]
  const float* rule = (const float*)d_in[2];   // [8, 4, 4, 4]
  const float* W    = (const float*)d_in[3];   // [8, 4, D/4, O/4]
  const float* bias = (const float*)d_in[4];   // [8, O]
  float* out = (float*)d_out;

  int D = in_sizes[1] / NEXP;
  int O = in_sizes[4] / NEXP;
  int T = in_sizes[0] / D;
  int Dp = D / 4, Op = O / 4;

  uint8_t* ws = (uint8_t*)d_ws;
  size_t off = 0;
  f16* xb = (f16*)(ws + off);  off += (size_t)T * D * 2;
  f16* wt = (f16*)(ws + off);  off += (size_t)NEXP * O * D * 2;
  int*   gate  = (int*)(ws + off);   off += (size_t)T * 4;
  float* scale = (float*)(ws + off); off += (size_t)T * 4;
  int*   perm  = (int*)(ws + off);   off += (size_t)T * 4;
  off = (off + 255) & ~(size_t)255;
  uint8_t* C = ws + off;
  int*   cnt     = (int*)(C + 0);
  float* probsum = (float*)(C + 32);
  int*   cursor  = (int*)(C + 64);
  int*   ndesc   = (int*)(C + 96);
  int*   offs    = (int*)(C + 128);
  int2*  desc    = (int2*)(C + 192);   // capacity to C+4096

  // zero cnt/probsum/cursor/ndesc (ws is re-poisoned 0xAA before every call)
  hipMemsetAsync(C, 0, 128, stream);

  k_gate<<<T / 4, 256, 0, stream>>>(x, gw, xb, gate, scale, cnt, probsum, D);
  k_wfull<<<NEXP * (Op / 32) * (Dp / 32), 256, 0, stream>>>(W, rule, wt, Dp, Op, D, O);
  k_plan<<<1, 1, 0, stream>>>(cnt, probsum, offs, ndesc, desc, out + (size_t)T * O, T);
  k_scatter<<<T / 256, 256, 0, stream>>>(gate, offs, cursor, perm);

  int maxdesc = T / BM + NEXP;  // worst-case row-block descriptor count
  k_gemm<<<dim3(O / BN, maxdesc), 256, 0, stream>>>(
      xb, wt, bias, perm, cnt, offs, ndesc, desc, scale, out, D, O);
}

// Round 4
// 339.900 us; speedup vs baseline: 1.1797x; 1.1447x over previous
//
#include <hip/hip_runtime.h>
#include <cstdint>
#include <cstddef>

typedef _Float16 f16;
typedef f16 f16x2 __attribute__((ext_vector_type(2)));
typedef f16 f16x4 __attribute__((ext_vector_type(4)));
typedef f16 f16x8 __attribute__((ext_vector_type(8)));
typedef float f32x4 __attribute__((ext_vector_type(4)));

#define NEXP 8
#define BM 128
#define BN 128
#define BK 32
#define NSTAGE 3

// async global->LDS, 16B per lane. LDS dest must be wave-uniform base + lane*16
// (staging index is tid*16 so this holds). Global source may be per-lane
// arbitrary (gathered rows / swizzled chunks are fine).
__device__ __forceinline__ void async_cp16(void* lds, const void* gsrc) {
  __builtin_amdgcn_global_load_lds(
      (const __attribute__((address_space(1))) void*)gsrc,
      (__attribute__((address_space(3))) void*)lds, 16, 0, 0);
}

// ---------------- K0: transpose gate weights gw[D,8] -> gwT[8,D] ----------------
__global__ __launch_bounds__(256) void k_gwT(const float* __restrict__ gw,
                                             float* __restrict__ gwT, int D) {
  int i = blockIdx.x * 256 + threadIdx.x;   // i < 8*D
  int e = i / D, d = i - e * D;
  gwT[i] = gw[d * NEXP + e];
}

// ---------------- K1: gating + x -> fp16 (single x pass, coalesced gwT) ------
// 256 threads = 4 waves, one token per wave. gwT (64KB) is L2-resident and
// every per-expert load is lane-contiguous (1 KB/wave-instr, 16 lines).
__global__ __launch_bounds__(256) void k_gate(
    const float* __restrict__ x, const float* __restrict__ gwT,
    f16* __restrict__ xb, int* __restrict__ gate, float* __restrict__ scale,
    int* __restrict__ cnt, float* __restrict__ probsum, int D)
{
  __shared__ float ps[NEXP];
  __shared__ int pc[NEXP];
  int tid = threadIdx.x, lane = tid & 63, w = tid >> 6;
  if (tid < NEXP) { ps[tid] = 0.f; pc[tid] = 0; }
  __syncthreads();

  int t = blockIdx.x * 4 + w;
  const float* xr = x + (size_t)t * D;
  f16* xbr = xb + (size_t)t * D;

  float acc[NEXP] = {};
  for (int d0 = lane * 4; d0 < D; d0 += 256) {
    float4 v = *(const float4*)(xr + d0);
    f16x4 h; h[0] = (f16)v.x; h[1] = (f16)v.y; h[2] = (f16)v.z; h[3] = (f16)v.w;
    *(f16x4*)(xbr + d0) = h;
#pragma unroll
    for (int e = 0; e < NEXP; e++) {
      float4 g = *(const float4*)(gwT + (size_t)e * D + d0);
      acc[e] += v.x * g.x + v.y * g.y + v.z * g.z + v.w * g.w;
    }
  }
#pragma unroll
  for (int e = 0; e < NEXP; e++) {
    float v = acc[e];
    for (int o = 32; o > 0; o >>= 1) v += __shfl_xor(v, o);
    acc[e] = v;
  }
  if (lane == 0) {
    float m = acc[0]; int g = 0;
#pragma unroll
    for (int e = 1; e < NEXP; e++) if (acc[e] > m) { m = acc[e]; g = e; }
    float pr[NEXP]; float ssum = 0.f;
#pragma unroll
    for (int e = 0; e < NEXP; e++) { pr[e] = __expf(acc[e] - m); ssum += pr[e]; }
    float inv = 1.0f / ssum;
#pragma unroll
    for (int e = 0; e < NEXP; e++) atomicAdd(&ps[e], pr[e] * inv);
    atomicAdd(&pc[g], 1);
    gate[t] = g;
    scale[t] = pr[g] * inv;
  }
  __syncthreads();
  if (tid < NEXP) {
    atomicAdd(&probsum[tid], ps[tid]);
    atomicAdd(&cnt[tid], pc[tid]);
  }
}

// ---------------- K2: build Wfull^T in fp16 ----------------
// wt[e][n][d] = sum_p rule[e,p,a,b] * W[e,p,i,j], d = a*Dp+i, n = b*Op+j.
// n-major, d contiguous. b looped in-block: W tile read once, used for all 4 b.
__global__ __launch_bounds__(256) void k_wfull(
    const float* __restrict__ Wp, const float* __restrict__ rule,
    f16* __restrict__ wt, int Dp, int Op, int D, int O)
{
  int bid = blockIdx.x;
  int it = Dp >> 5, jt = Op >> 5;
  int itile = bid % it; bid /= it;
  int jtile = bid % jt; bid /= jt;
  int e = bid;
  int i0 = itile * 32, j0 = jtile * 32;

  __shared__ float Wt[4][32][33];
  int tid = threadIdx.x;
  for (int idx = tid; idx < 4096; idx += 256) {
    int p = idx >> 10, rem = idx & 1023, ii = rem >> 5, jj = rem & 31;
    Wt[p][ii][jj] = Wp[(size_t)((e * 4 + p) * Dp + i0 + ii) * Op + j0 + jj];
  }
  __syncthreads();

  int ii = (tid & 15) * 2, jjb = tid >> 4;
#pragma unroll
  for (int b = 0; b < 4; b++) {
    float s[4][4];
#pragma unroll
    for (int p = 0; p < 4; p++)
#pragma unroll
      for (int a = 0; a < 4; a++)
        s[p][a] = rule[((e * 4 + p) * 4 + a) * 4 + b];
#pragma unroll
    for (int a = 0; a < 4; a++) {
#pragma unroll
      for (int jp = 0; jp < 2; jp++) {
        int jj = jjb + jp * 16;
        float v0 = 0.f, v1 = 0.f;
#pragma unroll
        for (int p = 0; p < 4; p++) {
          v0 += s[p][a] * Wt[p][ii][jj];
          v1 += s[p][a] * Wt[p][ii + 1][jj];
        }
        size_t n = (size_t)b * Op + j0 + jj;
        size_t dd = (size_t)a * Dp + i0 + ii;
        f16x2 hv; hv[0] = (f16)v0; hv[1] = (f16)v1;
        *(f16x2*)(wt + ((size_t)e * O + n) * D + dd) = hv;
      }
    }
  }
}

// ---------------- K3: plan (scan, loss, descriptors) ----------------
// Serial logic in LDS by thread 0 (16 global reads), then parallel writes
// (kills the ~80-deep serially-dependent global-write chain).
__global__ __launch_bounds__(128) void k_plan(
    const int* __restrict__ cnt, const float* __restrict__ probsum,
    int* __restrict__ offs, int* __restrict__ ndesc,
    int2* __restrict__ desc, float* __restrict__ otail, int T)
{
  __shared__ int soffs[NEXP + 1];
  __shared__ int snd;
  __shared__ float sloss;
  __shared__ int2 sdesc[96];
  int tid = threadIdx.x;
  if (tid == 0) {
    int off = 0, nd = 0; float loss = 0.f;
    for (int e = 0; e < NEXP; e++) {
      soffs[e] = off;
      int c = cnt[e];
      loss += probsum[e] * (float)c;
      for (int m0 = 0; m0 < c; m0 += BM) { sdesc[nd] = make_int2(e, m0); nd++; }
      off += c;
    }
    soffs[NEXP] = off;
    snd = nd;
    sloss = loss;
  }
  __syncthreads();
  if (tid <= NEXP) offs[tid] = soffs[tid];
  if (tid == 9) *ndesc = snd;
  if (tid == 10) {
    float invT = 1.0f / (float)T;
    otail[0] = (float)NEXP * sloss * invT * invT;  // balance loss
  }
  if (tid >= 16 && tid < 16 + NEXP) otail[1 + tid - 16] = (float)cnt[tid - 16];
  for (int i = tid; i < snd; i += 128) desc[i] = sdesc[i];
}

// ---------------- K4: scatter tokens by expert ----------------
__global__ __launch_bounds__(256) void k_scatter(
    const int* __restrict__ gate, const int* __restrict__ offs,
    int* __restrict__ cursor, int* __restrict__ perm)
{
  int t = blockIdx.x * 256 + threadIdx.x;
  int g = gate[t];
  int lane = threadIdx.x & 63;
  int pos = 0;
#pragma unroll
  for (int e = 0; e < NEXP; e++) {
    unsigned long long mask = __ballot(g == e);
    if (mask == 0ull) continue;            // wave-uniform
    int leader = __ffsll((unsigned long long)mask) - 1;
    int base = 0;
    if (lane == leader) base = atomicAdd(&cursor[e], (int)__popcll(mask));
    base = __shfl(base, leader);
    if (g == e) {
      int below = (int)__popcll(mask & ((1ull << lane) - 1ull));
      pos = offs[e] + base + below;
    }
  }
  perm[pos] = t;
}

// ---------------- K5: gathered top-1 GEMM ----------------
// 128x128 tile, BK=32, 3-stage LDS pipeline (prefetch distance 2), fine
// vmcnt barriers, XOR bank swizzle. Grid ncol-fastest for A/B cache reuse.
__global__ __launch_bounds__(256) void k_gemm(
    const f16* __restrict__ xb, const f16* __restrict__ wt,
    const float* __restrict__ bias, const int* __restrict__ perm,
    const int* __restrict__ cnt, const int* __restrict__ offs,
    const int* __restrict__ ndesc, const int2* __restrict__ desc,
    const float* __restrict__ scale, float* __restrict__ out, int D, int O)
{
  if ((int)blockIdx.y >= *ndesc) return;
  int2 dsc = desc[blockIdx.y];
  int e = dsc.x, m0 = dsc.y;
  int ce = cnt[e];
  int seg = offs[e];
  int n0 = blockIdx.x * BN;

  __shared__ f16 Al[NSTAGE][BM * BK];   // 3 x 8KB
  __shared__ f16 Bl[NSTAGE][BN * BK];   // 3 x 8KB
  __shared__ int tokS[BM];
  __shared__ float scS[BM];

  int tid = threadIdx.x;
  if (tid < BM) {
    int idx = m0 + tid; if (idx > ce - 1) idx = ce - 1;  // clamp partial tile
    int tok = perm[seg + idx];
    tokS[tid] = tok;
    scS[tid] = scale[tok];
  }
  __syncthreads();

  // staging: thread owns 16B chunk c of rows r and r+64; fetches global chunk
  // gc = c ^ ((r>>1)&3); MFMA reader un-swizzles with the same xor.
  int r = tid >> 2;   // 0..63
  int c = tid & 3;
  int gc = c ^ ((r >> 1) & 3);
  const f16* a1 = xb + (size_t)tokS[r] * D + gc * 8;
  const f16* a2 = xb + (size_t)tokS[r + 64] * D + gc * 8;
  const f16* b1 = wt + ((size_t)e * O + n0 + r) * D + gc * 8;
  const f16* b2 = wt + ((size_t)e * O + n0 + r + 64) * D + gc * 8;

  int lane = tid & 63;
  int w = tid >> 6;
  int wm = (w & 1) * 64, wn = (w >> 1) * 64;
  int lr = lane & 15, q = lane >> 4;
  int qs = q ^ ((lr >> 1) & 3);  // swizzled read chunk

  f32x4 acc[4][4] = {};
  int nk = D / BK;

#define STAGE(kk, p)                                             \
  do {                                                           \
    async_cp16(&Al[(p)][tid * 8], a1 + (kk) * BK);               \
    async_cp16(&Al[(p)][2048 + tid * 8], a2 + (kk) * BK);        \
    async_cp16(&Bl[(p)][tid * 8], b1 + (kk) * BK);               \
    async_cp16(&Bl[(p)][2048 + tid * 8], b2 + (kk) * BK);        \
  } while (0)

  STAGE(0, 0);
  STAGE(1, 1);
  STAGE(2, 2);

  int p = 0;
  for (int kk = 0; kk < nk; ++kk) {
    // tile kk must be complete; tiles kk+1, kk+2 (8 loads) may stay in flight
    int rem = nk - 1 - kk;
    if (rem >= 2)
      asm volatile("s_waitcnt vmcnt(8)\n\ts_barrier" ::: "memory");
    else if (rem == 1)
      asm volatile("s_waitcnt vmcnt(4)\n\ts_barrier" ::: "memory");
    else
      asm volatile("s_waitcnt vmcnt(0)\n\ts_barrier" ::: "memory");

    f16x8 af[4], bf[4];
#pragma unroll
    for (int mi = 0; mi < 4; mi++)
      af[mi] = *(const f16x8*)&Al[p][(wm + mi * 16 + lr) * BK + qs * 8];
#pragma unroll
    for (int ni = 0; ni < 4; ni++)
      bf[ni] = *(const f16x8*)&Bl[p][(wn + ni * 16 + lr) * BK + qs * 8];

    // all waves' ds_reads of buffer p done -> safe to restage it
    asm volatile("s_waitcnt lgkmcnt(0)\n\ts_barrier" ::: "memory");
    if (kk + NSTAGE < nk) STAGE(kk + NSTAGE, p);

#pragma unroll
    for (int mi = 0; mi < 4; mi++)
#pragma unroll
      for (int ni = 0; ni < 4; ni++)
        acc[mi][ni] = __builtin_amdgcn_mfma_f32_16x16x32_f16(
            af[mi], bf[ni], acc[mi][ni], 0, 0, 0);

    p++; if (p == NSTAGE) p = 0;
  }
#undef STAGE

  // epilogue: C/D layout col=lane&15, row=(lane>>4)*4+reg
  float bv[4];
#pragma unroll
  for (int ni = 0; ni < 4; ni++)
    bv[ni] = bias[(size_t)e * O + n0 + wn + ni * 16 + lr];
#pragma unroll
  for (int mi = 0; mi < 4; mi++) {
#pragma unroll
    for (int rg = 0; rg < 4; rg++) {
      int rl = wm + mi * 16 + q * 4 + rg;
      if (m0 + rl < ce) {
        float s = scS[rl];
        float* orow = out + (size_t)tokS[rl] * O + n0 + wn;
#pragma unroll
        for (int ni = 0; ni < 4; ni++)
          orow[ni * 16 + lr] = (acc[mi][ni][rg] + bv[ni]) * s;
      }
    }
  }
}

extern "C" void kernel_launch(void* const* d_in, const int* in_sizes, int n_in,
                              void* d_out, int out_size, void* d_ws, size_t ws_size,
                              hipStream_t stream)
{
  const float* x    = (const float*)d_in[0];   // [T, D]
  const float* gw   = (const float*)d_in[1];   // [D, 8]
  const float* rule = (const float*)d_in[2];   // [8, 4, 4, 4]
  const float* W    = (const float*)d_in[3];   // [8, 4, D/4, O/4]
  const float* bias = (const float*)d_in[4];   // [8, O]
  float* out = (float*)d_out;

  int D = in_sizes[1] / NEXP;
  int O = in_sizes[4] / NEXP;
  int T = in_sizes[0] / D;
  int Dp = D / 4, Op = O / 4;

  uint8_t* ws = (uint8_t*)d_ws;
  size_t off = 0;
  f16* xb = (f16*)(ws + off);  off += (size_t)T * D * 2;
  f16* wt = (f16*)(ws + off);  off += (size_t)NEXP * O * D * 2;
  int*   gate  = (int*)(ws + off);   off += (size_t)T * 4;
  float* scale = (float*)(ws + off); off += (size_t)T * 4;
  int*   perm  = (int*)(ws + off);   off += (size_t)T * 4;
  off = (off + 255) & ~(size_t)255;
  uint8_t* C = ws + off;
  int*   cnt     = (int*)(C + 0);
  float* probsum = (float*)(C + 32);
  int*   cursor  = (int*)(C + 64);
  int*   ndesc   = (int*)(C + 96);
  int*   offs    = (int*)(C + 128);
  int2*  desc    = (int2*)(C + 192);   // capacity to C+4096
  float* gwT     = (float*)(C + 4096); // [8, D] fp32

  // zero cnt/probsum/cursor/ndesc (ws is re-poisoned 0xAA before every call)
  hipMemsetAsync(C, 0, 128, stream);

  k_gwT<<<(NEXP * D) / 256, 256, 0, stream>>>(gw, gwT, D);
  k_gate<<<T / 4, 256, 0, stream>>>(x, gwT, xb, gate, scale, cnt, probsum, D);
  k_wfull<<<NEXP * (Op / 32) * (Dp / 32), 256, 0, stream>>>(W, rule, wt, Dp, Op, D, O);
  k_plan<<<1, 128, 0, stream>>>(cnt, probsum, offs, ndesc, desc, out + (size_t)T * O, T);
  k_scatter<<<T / 256, 256, 0, stream>>>(gate, offs, cursor, perm);

  int maxdesc = T / BM + NEXP;  // worst-case row-block descriptor count
  k_gemm<<<dim3(O / BN, maxdesc), 256, 0, stream>>>(
      xb, wt, bias, perm, cnt, offs, ndesc, desc, scale, out, D, O);
}